// Round 5
// baseline (354.073 us; speedup 1.0000x reference)
//
#include <hip/hip_runtime.h>

// out = min_co( conv2d(x, W, SAME) ) * 2
// x (32,64,128,128) fp32, W (128,64,3,3) fp32 -> out (32,1,128,128) fp32
//
// Round 5: persistent blocks + LDS ring buffer.
//  grid = 256 blocks (1/CU), 512 thr (8 waves: 4 wm x 2 wn, 4x4 frags).
//  Each block: batch b, 16 output rows. LDS ring of 8 padded rows
//  (slot = (row+1)&7). Per iteration (2 output rows): issue global loads for
//  2 new rows -> K-loop (18 steps, 16 MFMA each, B reg-prefetched from L2)
//  -> pack+ds_write_b128 new rows into disjoint slots -> min-epilogue,
//  ONE barrier. x is read exactly once from HBM.
//  Staging writes: lane->w stride 32 => wp&7 spans 8 values => b128 writes
//  hit all 32 banks per pass => conflict-free (vs R4's 16-way).

typedef __attribute__((ext_vector_type(8))) short  short8;   // 8 x bf16
typedef __attribute__((ext_vector_type(4))) float  float4v;
typedef __attribute__((ext_vector_type(4))) unsigned int uint4v;

#define CI 64
#define CO 128
#define HH 128
#define WW 128
#define WP 130
#define ROWB (WP * 128)                      // 16,640 B per padded row
#define WT_BYTES ((size_t)9 * CO * CI * 2)   // 147,456

__device__ __forceinline__ unsigned short f2bf(float f) {
    unsigned int u = __float_as_uint(f);
    u = (u + 0x7fffu + ((u >> 16) & 1u)) >> 16;   // RNE
    return (unsigned short)u;
}
__device__ __forceinline__ unsigned int pack2(float a, float b) {
    return (unsigned int)f2bf(a) | ((unsigned int)f2bf(b) << 16);
}

// ---------------- prep_w: W (co,ci,3,3) fp32 -> wt[tap][co][ci] bf16 ------

__global__ __launch_bounds__(256) void prep_w(
    const float* __restrict__ Wsrc, unsigned short* __restrict__ wt)
{
    int idx = blockIdx.x * 256 + threadIdx.x;          // (tap, co, ci)
    if (idx >= 9 * CO * CI) return;
    int ci  = idx & 63;
    int t   = idx >> 6;
    int co  = t & 127;
    int tap = t >> 7;
    wt[idx] = f2bf(Wsrc[((size_t)co * CI + ci) * 9 + tap]);
}

// ---------------- persistent fused conv + min ----------------

__global__ __launch_bounds__(512, 2) void conv_persist(
    const float* __restrict__ x,
    const unsigned short* __restrict__ wt,
    float* __restrict__ out)
{
    __shared__ __align__(16) char  ldsA[8 * ROWB];     // 133,120 B ring
    __shared__ float scratch[2][2][256];               // 4 KB, rp-parity dbuf

    const int chunk = blockIdx.x;      // 0..7 : output rows [16c, 16c+16)
    const int b     = blockIdx.y;
    const int tid   = threadIdx.x;
    const int lane  = tid & 63;
    const int wid   = tid >> 6;
    const int l15   = lane & 15;
    const int quad  = lane >> 4;
    const int wm    = wid & 3;         // m quarter (64 of 256 pixels)
    const int wn    = wid >> 2;        // co half (64 of 128)
    const int n0    = wn * 64;
    const int c16   = chunk * 16;

    // staging role: wq = w mod 32, co8 = ci octet, rr = which of 2 rows
    const int wq  = tid & 31;
    const int co8 = (tid >> 5) & 7;
    const int rr  = tid >> 8;

    const float* xb = x + ((size_t)b * CI + co8 * 8) * HH * WW + wq;

    // ---- zero pad columns wp=0,129 of all 8 ring slots ----
    if (tid < 128) {
        int slot = tid >> 4;
        int wpp  = ((tid >> 3) & 1) ? 129 : 0;
        int q    = tid & 7;
        *(float4v*)(ldsA + slot * ROWB + wpp * 128 + q * 16) =
            (float4v){0.f, 0.f, 0.f, 0.f};
    }

    // ---- stage one padded row (abs index `row`, slot=(row+1)&7) ----
    auto stage = [&](int row) {
        float v[8][4];
        if (row >= 0 && row < HH) {
            const float* rp_ = xb + (size_t)row * WW;
            #pragma unroll
            for (int k = 0; k < 8; ++k) {
                const float* pk = rp_ + (size_t)k * HH * WW;
                #pragma unroll
                for (int e = 0; e < 4; ++e) v[k][e] = pk[32 * e];
            }
        } else {
            #pragma unroll
            for (int k = 0; k < 8; ++k)
                #pragma unroll
                for (int e = 0; e < 4; ++e) v[k][e] = 0.f;
        }
        char* sbase = ldsA + ((row + 1) & 7) * ROWB;
        #pragma unroll
        for (int e = 0; e < 4; ++e) {
            int wpp = wq + 32 * e + 1;
            int s16 = co8 ^ (wpp & 7);
            uint4v q4;
            q4.x = pack2(v[0][e], v[1][e]);
            q4.y = pack2(v[2][e], v[3][e]);
            q4.z = pack2(v[4][e], v[5][e]);
            q4.w = pack2(v[6][e], v[7][e]);
            *(uint4v*)(sbase + wpp * 128 + s16 * 16) = q4;
        }
    };

    // prologue: rows c16-1 .. c16+2 (rr splits the pair)
    stage(c16 - 1 + rr);
    stage(c16 + 1 + rr);
    __syncthreads();

    const unsigned short* wt_lane = wt + (size_t)(n0 + l15) * CI + quad * 8;
    const int pxo    = ((wm & 1) << 6) + l15;   // pixel base within row
    const int rhalf  = wm >> 1;                 // which output row of pair

    #pragma unroll 1
    for (int rp = 0; rp < 8; ++rp) {
        const int r0   = c16 + 2 * rp;
        const bool dopf = (rp < 7);
        const int prow  = r0 + 3 + rr;          // this thread's prefetch row

        // ---- issue global loads for the 2 new rows (land during K-loop) ----
        float v[8][4];
        if (dopf && prow < HH) {
            const float* rp_ = xb + (size_t)prow * WW;
            #pragma unroll
            for (int k = 0; k < 8; ++k) {
                const float* pk = rp_ + (size_t)k * HH * WW;
                #pragma unroll
                for (int e = 0; e < 4; ++e) v[k][e] = pk[32 * e];
            }
        } else {
            #pragma unroll
            for (int k = 0; k < 8; ++k)
                #pragma unroll
                for (int e = 0; e < 4; ++e) v[k][e] = 0.f;
        }

        // ---- K-loop: 9 taps x 2 kc, slots {2rp..2rp+3} ----
        float4v acc[4][4];
        #pragma unroll
        for (int mt = 0; mt < 4; ++mt)
            #pragma unroll
            for (int nt = 0; nt < 4; ++nt)
                acc[mt][nt] = (float4v){0.f, 0.f, 0.f, 0.f};

        short8 bcur[4], bnxt[4];
        #pragma unroll
        for (int nt = 0; nt < 4; ++nt)
            bcur[nt] = *(const short8*)(wt_lane + nt * 16 * CI);

        #pragma unroll
        for (int it = 0; it < 18; ++it) {
            const int tap = it >> 1;
            const int kc  = it & 1;
            const int dh  = tap / 3;
            const int dw  = tap % 3;

            if (it < 17) {                     // prefetch next B fragments
                const int tn   = it + 1;
                const size_t o = (size_t)(tn >> 1) * CO * CI
                               + (size_t)(tn & 1) * 32;
                #pragma unroll
                for (int nt = 0; nt < 4; ++nt)
                    bnxt[nt] = *(const short8*)(wt_lane + o + nt * 16 * CI);
            }

            const int slot = (r0 + rhalf + dh) & 7;
            const int sp   = ((kc * 4 + quad) ^ ((dw + l15) & 7)) * 16;
            const char* abase = ldsA + slot * ROWB + (pxo + dw) * 128 + sp;

            short8 af[4];
            #pragma unroll
            for (int mt = 0; mt < 4; ++mt)
                af[mt] = *(const short8*)(abase + mt * 16 * 128);

            #pragma unroll
            for (int mt = 0; mt < 4; ++mt)
                #pragma unroll
                for (int nt = 0; nt < 4; ++nt)
                    acc[mt][nt] = __builtin_amdgcn_mfma_f32_16x16x32_bf16(
                        af[mt], bcur[nt], acc[mt][nt], 0, 0, 0);

            #pragma unroll
            for (int nt = 0; nt < 4; ++nt) bcur[nt] = bnxt[nt];
        }

        // ---- write prefetched rows into ring slots {2rp+4, 2rp+5} ----
        if (dopf) {
            char* sbase = ldsA + ((prow + 1) & 7) * ROWB;
            #pragma unroll
            for (int e = 0; e < 4; ++e) {
                int wpp = wq + 32 * e + 1;
                int s16 = co8 ^ (wpp & 7);
                uint4v q4;
                q4.x = pack2(v[0][e], v[1][e]);
                q4.y = pack2(v[2][e], v[3][e]);
                q4.z = pack2(v[4][e], v[5][e]);
                q4.w = pack2(v[6][e], v[7][e]);
                *(uint4v*)(sbase + wpp * 128 + s16 * 16) = q4;
            }
        }

        // ---- epilogue: min over co, *2 ----
        // lane holds D[m = 64wm+16mt+quad*4+reg][n = n0+16nt+l15]
        float pm[4][4];
        #pragma unroll
        for (int mt = 0; mt < 4; ++mt)
            #pragma unroll
            for (int reg = 0; reg < 4; ++reg) {
                float t0 = fminf(acc[mt][0][reg], acc[mt][1][reg]);
                float t1 = fminf(acc[mt][2][reg], acc[mt][3][reg]);
                pm[mt][reg] = fminf(t0, t1);
            }
        #pragma unroll
        for (int mask = 1; mask <= 8; mask <<= 1)
            #pragma unroll
            for (int mt = 0; mt < 4; ++mt)
                #pragma unroll
                for (int reg = 0; reg < 4; ++reg)
                    pm[mt][reg] = fminf(pm[mt][reg],
                                        __shfl_xor(pm[mt][reg], mask, 64));
        if (l15 == 0) {
            #pragma unroll
            for (int mt = 0; mt < 4; ++mt)
                #pragma unroll
                for (int reg = 0; reg < 4; ++reg)
                    scratch[rp & 1][wn]
                           [(wm << 6) + (mt << 4) + (quad << 2) + reg]
                        = pm[mt][reg];
        }
        __syncthreads();
        if (tid < 256) {
            float vv = fminf(scratch[rp & 1][0][tid],
                             scratch[rp & 1][1][tid]) * 2.0f;
            out[((size_t)b * HH + r0 + (tid >> 7)) * WW + (tid & 127)] = vv;
        }
    }
}

// ---------------- fallback (round-1 direct conv) ----------------

#define COT 16
__global__ __launch_bounds__(256) void conv_min_fallback(
    const float* __restrict__ x, const float* __restrict__ Wt,
    float* __restrict__ out)
{
    const int b  = blockIdx.y;
    const int h  = blockIdx.x * 2 + (threadIdx.x >> 7);
    const int w  = threadIdx.x & 127;
    const bool r0 = h > 0, r2 = h < HH - 1, c0 = w > 0, c2 = w < WW - 1;
    const float* xb = x + (size_t)b * CI * HH * WW;
    float vmin = 3.4e38f;
    for (int cb = 0; cb < CO; cb += COT) {
        float acc[COT];
        #pragma unroll
        for (int u = 0; u < COT; ++u) acc[u] = 0.0f;
        #pragma unroll 1
        for (int ci = 0; ci < CI; ++ci) {
            const float* xp = xb + ((size_t)ci * HH + h) * WW + w;
            float xv[9];
            xv[0] = (r0 && c0) ? xp[-WW - 1] : 0.0f;
            xv[1] =  r0        ? xp[-WW    ] : 0.0f;
            xv[2] = (r0 && c2) ? xp[-WW + 1] : 0.0f;
            xv[3] =        c0  ? xp[-1     ] : 0.0f;
            xv[4] =              xp[0      ];
            xv[5] =        c2  ? xp[1      ] : 0.0f;
            xv[6] = (r2 && c0) ? xp[ WW - 1] : 0.0f;
            xv[7] =  r2        ? xp[ WW    ] : 0.0f;
            xv[8] = (r2 && c2) ? xp[ WW + 1] : 0.0f;
            #pragma unroll
            for (int u = 0; u < COT; ++u) {
                const float* wp = Wt + ((size_t)(cb + u) * CI + ci) * 9;
                acc[u] += wp[0]*xv[0] + wp[1]*xv[1] + wp[2]*xv[2]
                        + wp[3]*xv[3] + wp[4]*xv[4] + wp[5]*xv[5]
                        + wp[6]*xv[6] + wp[7]*xv[7] + wp[8]*xv[8];
            }
        }
        #pragma unroll
        for (int u = 0; u < COT; ++u) vmin = fminf(vmin, acc[u]);
    }
    out[((size_t)b * HH + h) * WW + w] = vmin * 2.0f;
}

// ---------------- launch ----------------

extern "C" void kernel_launch(void* const* d_in, const int* in_sizes, int n_in,
                              void* d_out, int out_size, void* d_ws, size_t ws_size,
                              hipStream_t stream) {
    const float* x  = (const float*)d_in[0];   // (32,64,128,128)
    const float* Ws = (const float*)d_in[1];   // (128,64,3,3)
    float* out = (float*)d_out;                // (32,1,128,128)

    if (ws_size < WT_BYTES) {
        dim3 grid(HH / 2, 32);
        conv_min_fallback<<<grid, 256, 0, stream>>>(x, Ws, out);
        return;
    }

    unsigned short* wt = (unsigned short*)d_ws;

    prep_w<<<(9 * CO * CI + 255) / 256, 256, 0, stream>>>(Ws, wt);
    conv_persist<<<dim3(8, 32), 512, 0, stream>>>(x, wt, out);
}

// Round 6
// 316.716 us; speedup vs baseline: 1.1180x; 1.1180x over previous
//
#include <hip/hip_runtime.h>

// out = min_co( conv2d(x, W, SAME) ) * 2
// x (32,64,128,128) fp32, W (128,64,3,3) fp32 -> out (32,1,128,128) fp32
//
// Round 6: two-phase fused kernel (R4 flow + R5 staging pattern + 4x4 frags).
//  grid 64x32, 512 thr (8 waves: 4 wm x 2 wn). Per block: 2 output rows.
//  Phase 1: stage 4 padded x rows -> bf16 transposed swizzled LDS
//           (8ci/thread b128 writes, w-stride 32 => conflict-free, per R5).
//           Staging regs transient (per-e chunks) => no K-loop spill (R5 bug).
//  Phase 2: K-loop 9 taps x 2 kc, 16 MFMA/step, B reg-double-buffered from L2.
//  Epilogue: min over co (shfl butterfly + LDS), *2, coalesced store.
//  VGPR budget: acc 64 (AGPR) + bcur/bnxt 32 + af 16 + addr ~10 <= 128 @ 4 w/EU.

typedef __attribute__((ext_vector_type(8))) short  short8;   // 8 x bf16
typedef __attribute__((ext_vector_type(4))) float  float4v;
typedef __attribute__((ext_vector_type(4))) unsigned int uint4v;

#define CI 64
#define CO 128
#define HH 128
#define WW 128
#define WP 130
#define ROWB (WP * 128)                      // 16,640 B per padded row
#define WT_BYTES ((size_t)9 * CO * CI * 2)   // 147,456

__device__ __forceinline__ unsigned short f2bf(float f) {
    unsigned int u = __float_as_uint(f);
    u = (u + 0x7fffu + ((u >> 16) & 1u)) >> 16;   // RNE
    return (unsigned short)u;
}
__device__ __forceinline__ unsigned int pack2(float a, float b) {
    return (unsigned int)f2bf(a) | ((unsigned int)f2bf(b) << 16);
}

// ---------------- prep_w: W (co,ci,3,3) fp32 -> wt[tap][co][ci] bf16 ------

__global__ __launch_bounds__(256) void prep_w(
    const float* __restrict__ Wsrc, unsigned short* __restrict__ wt)
{
    int idx = blockIdx.x * 256 + threadIdx.x;          // (tap, co, ci)
    if (idx >= 9 * CO * CI) return;
    int ci  = idx & 63;
    int t   = idx >> 6;
    int co  = t & 127;
    int tap = t >> 7;
    wt[idx] = f2bf(Wsrc[((size_t)co * CI + ci) * 9 + tap]);
}

// ---------------- fused conv + min ----------------

#define LDSA_BYTES (4 * ROWB)   // 66,560

__global__ __launch_bounds__(512, 4) void conv_fused(
    const float* __restrict__ x,
    const unsigned short* __restrict__ wt,
    float* __restrict__ out)
{
    __shared__ __align__(16) char  ldsA[LDSA_BYTES];
    __shared__ float scratch[2][256];

    const int bx   = blockIdx.x;       // output rows 2bx, 2bx+1
    const int b    = blockIdx.y;
    const int tid  = threadIdx.x;
    const int lane = tid & 63;
    const int wid  = tid >> 6;
    const int l15  = lane & 15;
    const int quad = lane >> 4;
    const int wm   = wid & 3;          // m quarter of the 256-pixel tile
    const int wn   = wid >> 2;         // co half
    const int n0   = wn * 64;

    // staging role: wq = w mod 32, co8 = ci octet, rr = row parity
    const int wq  = tid & 31;
    const int co8 = (tid >> 5) & 7;
    const int rr  = tid >> 8;
    const float* xb = x + ((size_t)b * CI + co8 * 8) * HH * WW + wq;

    // ---- zero pad columns wp=0,129 of all 4 LDS rows ----
    if (tid < 64) {
        int slot = tid >> 4;
        int wpp  = ((tid >> 3) & 1) ? 129 : 0;
        int q    = tid & 7;
        *(float4v*)(ldsA + slot * ROWB + wpp * 128 + q * 16) =
            (float4v){0.f, 0.f, 0.f, 0.f};
    }

    // ---- phase 1: stage 4 padded rows (transient registers only) ----
    auto stage = [&](int row, int slot) {
        char* sbase = ldsA + slot * ROWB;
        const bool inb = (row >= 0 && row < HH);        // wave-uniform
        const float* rp_ = xb + (size_t)row * WW;
        #pragma unroll
        for (int e = 0; e < 4; ++e) {
            float v[8];
            #pragma unroll
            for (int k = 0; k < 8; ++k)
                v[k] = inb ? rp_[(size_t)k * HH * WW + 32 * e] : 0.f;
            const int wpp = wq + 32 * e + 1;            // 1..128
            const int s16 = co8 ^ (wpp & 7);            // 16B-slot swizzle
            uint4v q4;
            q4.x = pack2(v[0], v[1]);
            q4.y = pack2(v[2], v[3]);
            q4.z = pack2(v[4], v[5]);
            q4.w = pack2(v[6], v[7]);
            *(uint4v*)(sbase + wpp * 128 + s16 * 16) = q4;
        }
    };
    stage(2 * bx - 1 + rr, rr);          // rows -1,0 -> slots 0,1
    stage(2 * bx + 1 + rr, 2 + rr);      // rows +1,+2 -> slots 2,3
    __syncthreads();

    // ---- phase 2: K-loop, 9 taps x 2 kc, B register-double-buffered ----
    float4v acc[4][4];
    #pragma unroll
    for (int mt = 0; mt < 4; ++mt)
        #pragma unroll
        for (int nt = 0; nt < 4; ++nt)
            acc[mt][nt] = (float4v){0.f, 0.f, 0.f, 0.f};

    const unsigned short* wt_lane = wt + (size_t)(n0 + l15) * CI + quad * 8;
    const int rhalf = wm >> 1;                 // which output row of the pair
    const int pxo   = ((wm & 1) << 6) + l15;   // pixel base within row

    short8 bcur[4], bnxt[4];
    #pragma unroll
    for (int nt = 0; nt < 4; ++nt)
        bcur[nt] = *(const short8*)(wt_lane + nt * 16 * CI);

    #pragma unroll
    for (int it = 0; it < 18; ++it) {
        const int tap = it >> 1;
        const int kc  = it & 1;
        const int dh  = tap / 3;
        const int dw  = tap % 3;

        if (it < 17) {                         // prefetch next B fragments
            const int tn   = it + 1;
            const size_t o = (size_t)(tn >> 1) * CO * CI
                           + (size_t)(tn & 1) * 32;
            #pragma unroll
            for (int nt = 0; nt < 4; ++nt)
                bnxt[nt] = *(const short8*)(wt_lane + o + nt * 16 * CI);
        }

        const int sp = ((kc * 4 + quad) ^ ((dw + l15) & 7)) * 16;
        const char* abase = ldsA
            + (size_t)((rhalf + dh) * WP + pxo + dw) * 128 + sp;

        short8 af[4];
        #pragma unroll
        for (int mt = 0; mt < 4; ++mt)
            af[mt] = *(const short8*)(abase + mt * 16 * 128);

        #pragma unroll
        for (int mt = 0; mt < 4; ++mt)
            #pragma unroll
            for (int nt = 0; nt < 4; ++nt)
                acc[mt][nt] = __builtin_amdgcn_mfma_f32_16x16x32_bf16(
                    af[mt], bcur[nt], acc[mt][nt], 0, 0, 0);

        #pragma unroll
        for (int nt = 0; nt < 4; ++nt) bcur[nt] = bnxt[nt];
    }

    // ---- epilogue: min over co, *2 ----
    // lane holds D[m = 64wm+16mt+4quad+reg][n = n0+16nt+l15]
    float pm[4][4];
    #pragma unroll
    for (int mt = 0; mt < 4; ++mt)
        #pragma unroll
        for (int reg = 0; reg < 4; ++reg) {
            float t0 = fminf(acc[mt][0][reg], acc[mt][1][reg]);
            float t1 = fminf(acc[mt][2][reg], acc[mt][3][reg]);
            pm[mt][reg] = fminf(t0, t1);
        }
    #pragma unroll
    for (int mask = 1; mask <= 8; mask <<= 1)
        #pragma unroll
        for (int mt = 0; mt < 4; ++mt)
            #pragma unroll
            for (int reg = 0; reg < 4; ++reg)
                pm[mt][reg] = fminf(pm[mt][reg],
                                    __shfl_xor(pm[mt][reg], mask, 64));
    if (l15 == 0) {
        #pragma unroll
        for (int mt = 0; mt < 4; ++mt)
            #pragma unroll
            for (int reg = 0; reg < 4; ++reg)
                scratch[wn][(wm << 6) + (mt << 4) + (quad << 2) + reg]
                    = pm[mt][reg];
    }
    __syncthreads();
    if (tid < 256) {
        float vv = fminf(scratch[0][tid], scratch[1][tid]) * 2.0f;
        out[((size_t)b * HH + 2 * bx + (tid >> 7)) * WW + (tid & 127)] = vv;
    }
}

// ---------------- fallback (round-1 direct conv) ----------------

#define COT 16
__global__ __launch_bounds__(256) void conv_min_fallback(
    const float* __restrict__ x, const float* __restrict__ Wt,
    float* __restrict__ out)
{
    const int b  = blockIdx.y;
    const int h  = blockIdx.x * 2 + (threadIdx.x >> 7);
    const int w  = threadIdx.x & 127;
    const bool r0 = h > 0, r2 = h < HH - 1, c0 = w > 0, c2 = w < WW - 1;
    const float* xb = x + (size_t)b * CI * HH * WW;
    float vmin = 3.4e38f;
    for (int cb = 0; cb < CO; cb += COT) {
        float acc[COT];
        #pragma unroll
        for (int u = 0; u < COT; ++u) acc[u] = 0.0f;
        #pragma unroll 1
        for (int ci = 0; ci < CI; ++ci) {
            const float* xp = xb + ((size_t)ci * HH + h) * WW + w;
            float xv[9];
            xv[0] = (r0 && c0) ? xp[-WW - 1] : 0.0f;
            xv[1] =  r0        ? xp[-WW    ] : 0.0f;
            xv[2] = (r0 && c2) ? xp[-WW + 1] : 0.0f;
            xv[3] =        c0  ? xp[-1     ] : 0.0f;
            xv[4] =              xp[0      ];
            xv[5] =        c2  ? xp[1      ] : 0.0f;
            xv[6] = (r2 && c0) ? xp[ WW - 1] : 0.0f;
            xv[7] =  r2        ? xp[ WW    ] : 0.0f;
            xv[8] = (r2 && c2) ? xp[ WW + 1] : 0.0f;
            #pragma unroll
            for (int u = 0; u < COT; ++u) {
                const float* wp = Wt + ((size_t)(cb + u) * CI + ci) * 9;
                acc[u] += wp[0]*xv[0] + wp[1]*xv[1] + wp[2]*xv[2]
                        + wp[3]*xv[3] + wp[4]*xv[4] + wp[5]*xv[5]
                        + wp[6]*xv[6] + wp[7]*xv[7] + wp[8]*xv[8];
            }
        }
        #pragma unroll
        for (int u = 0; u < COT; ++u) vmin = fminf(vmin, acc[u]);
    }
    out[((size_t)b * HH + h) * WW + w] = vmin * 2.0f;
}

// ---------------- launch ----------------

extern "C" void kernel_launch(void* const* d_in, const int* in_sizes, int n_in,
                              void* d_out, int out_size, void* d_ws, size_t ws_size,
                              hipStream_t stream) {
    const float* x  = (const float*)d_in[0];   // (32,64,128,128)
    const float* Ws = (const float*)d_in[1];   // (128,64,3,3)
    float* out = (float*)d_out;                // (32,1,128,128)

    if (ws_size < WT_BYTES) {
        dim3 grid(HH / 2, 32);
        conv_min_fallback<<<grid, 256, 0, stream>>>(x, Ws, out);
        return;
    }

    unsigned short* wt = (unsigned short*)d_ws;

    prep_w<<<(9 * CO * CI + 255) / 256, 256, 0, stream>>>(Ws, wt);
    conv_fused<<<dim3(HH / 2, 32), 512, 0, stream>>>(x, wt, out);
}

// Round 7
// 304.108 us; speedup vs baseline: 1.1643x; 1.0415x over previous
//
#include <hip/hip_runtime.h>

// out = min_co( conv2d(x, W, SAME) ) * 2
// x (32,64,128,128) fp32, W (128,64,3,3) fp32 -> out (32,1,128,128) fp32
//
// Round 7: R6 structure with co-designed staging:
//  - threads own 4-consecutive-w quads => 16 dwordx4 global loads/thread
//    (was 64 scalar loads in R6 — the R6 regression).
//  - slot swizzle g(wp) = (wp + (wp>>3)) & 7: 8 consecutive lanes -> 8
//    distinct slots => b128 LDS writes conflict-free even with w-quad lanes.
//    Reads: (p+16mt)>>3 == p>>3 + 2mt exactly => slot_mt = (g0 + 2mt)&7.
//  - pack2 via 2x(bfe+add3) + v_perm_b32: 5 VALU per 2 elements.
//  grid 64x32, 512 thr (8 waves: 4 wm x 2 wn), 4x4 frags, B reg-dbuf from L2.

typedef __attribute__((ext_vector_type(8))) short  short8;   // 8 x bf16
typedef __attribute__((ext_vector_type(4))) float  float4v;
typedef __attribute__((ext_vector_type(4))) unsigned int uint4v;

#define CI 64
#define CO 128
#define HH 128
#define WW 128
#define WP 130
#define ROWB (WP * 128)                      // 16,640 B per padded row
#define WT_BYTES ((size_t)9 * CO * CI * 2)   // 147,456

__device__ __forceinline__ unsigned short f2bf(float f) {
    unsigned int u = __float_as_uint(f);
    u = (u + 0x7fffu + ((u >> 16) & 1u)) >> 16;   // RNE
    return (unsigned short)u;
}

// RNE-round both floats to bf16, pack (b hi | a lo) in one v_perm_b32.
__device__ __forceinline__ unsigned int pack2(float a, float b) {
    unsigned int ua = __float_as_uint(a), ub = __float_as_uint(b);
    ua += 0x7fffu + ((ua >> 16) & 1u);
    ub += 0x7fffu + ((ub >> 16) & 1u);
    return __builtin_amdgcn_perm(ub, ua, 0x07060302);
}

// ---------------- prep_w: W (co,ci,3,3) fp32 -> wt[tap][co][ci] bf16 ------

__global__ __launch_bounds__(256) void prep_w(
    const float* __restrict__ Wsrc, unsigned short* __restrict__ wt)
{
    int idx = blockIdx.x * 256 + threadIdx.x;          // (tap, co, ci)
    if (idx >= 9 * CO * CI) return;
    int ci  = idx & 63;
    int t   = idx >> 6;
    int co  = t & 127;
    int tap = t >> 7;
    wt[idx] = f2bf(Wsrc[((size_t)co * CI + ci) * 9 + tap]);
}

// ---------------- fused conv + min ----------------

#define LDSA_BYTES (4 * ROWB)   // 66,560

__global__ __launch_bounds__(512, 4) void conv_fused(
    const float* __restrict__ x,
    const unsigned short* __restrict__ wt,
    float* __restrict__ out)
{
    __shared__ __align__(16) char  ldsA[LDSA_BYTES];
    __shared__ float scratch[2][256];

    const int bx   = blockIdx.x;       // output rows 2bx, 2bx+1
    const int b    = blockIdx.y;
    const int tid  = threadIdx.x;
    const int lane = tid & 63;
    const int wid  = tid >> 6;
    const int l15  = lane & 15;
    const int quad = lane >> 4;
    const int wm   = wid & 3;          // m quarter of the 256-pixel tile
    const int wn   = wid >> 2;         // co half
    const int n0   = wn * 64;

    // staging role: wqd = w quad (4 consecutive w), co8 = ci octet, rr = row
    const int wqd = tid & 31;
    const int co8 = (tid >> 5) & 7;
    const int rr  = tid >> 8;
    const float* xb = x + ((size_t)b * CI + co8 * 8) * HH * WW + 4 * wqd;

    // ---- zero pad columns wp=0,129 of all 4 LDS rows ----
    if (tid < 64) {
        int slot = tid >> 4;
        int wpp  = ((tid >> 3) & 1) ? 129 : 0;
        int q    = tid & 7;
        *(float4v*)(ldsA + slot * ROWB + wpp * 128 + q * 16) =
            (float4v){0.f, 0.f, 0.f, 0.f};
    }

    // ---- phase 1: stage 4 padded rows (transient registers only) ----
    auto stage = [&](int row, int slot) {
        char* sbase = ldsA + slot * ROWB;
        float4v f[8];
        if (row >= 0 && row < HH) {                     // wave-uniform
            const float* rp_ = xb + (size_t)row * WW;
            #pragma unroll
            for (int k = 0; k < 8; ++k)
                f[k] = *(const float4v*)(rp_ + (size_t)k * HH * WW);
        } else {
            #pragma unroll
            for (int k = 0; k < 8; ++k)
                f[k] = (float4v){0.f, 0.f, 0.f, 0.f};
        }
        #pragma unroll
        for (int e = 0; e < 4; ++e) {
            const int wpp = 4 * wqd + e + 1;            // 1..128
            const int gw  = (wpp + (wpp >> 3)) & 7;     // non-linear swizzle
            const int s16 = co8 ^ gw;
            uint4v q4;
            q4.x = pack2(f[0][e], f[1][e]);
            q4.y = pack2(f[2][e], f[3][e]);
            q4.z = pack2(f[4][e], f[5][e]);
            q4.w = pack2(f[6][e], f[7][e]);
            *(uint4v*)(sbase + wpp * 128 + s16 * 16) = q4;
        }
    };
    stage(2 * bx - 1 + rr, rr);          // rows -1,0 -> slots 0,1
    stage(2 * bx + 1 + rr, 2 + rr);      // rows +1,+2 -> slots 2,3
    __syncthreads();

    // ---- phase 2: K-loop, 9 taps x 2 kc, B register-double-buffered ----
    float4v acc[4][4];
    #pragma unroll
    for (int mt = 0; mt < 4; ++mt)
        #pragma unroll
        for (int nt = 0; nt < 4; ++nt)
            acc[mt][nt] = (float4v){0.f, 0.f, 0.f, 0.f};

    const unsigned short* wt_lane = wt + (size_t)(n0 + l15) * CI + quad * 8;
    const int rhalf = wm >> 1;                 // which output row of the pair
    const int pxo   = ((wm & 1) << 6) + l15;   // pixel base within row

    short8 bcur[4], bnxt[4];
    #pragma unroll
    for (int nt = 0; nt < 4; ++nt)
        bcur[nt] = *(const short8*)(wt_lane + nt * 16 * CI);

    #pragma unroll
    for (int it = 0; it < 18; ++it) {
        const int tap = it >> 1;
        const int kc  = it & 1;
        const int dh  = tap / 3;
        const int dw  = tap % 3;

        if (it < 17) {                         // prefetch next B fragments
            const int tn   = it + 1;
            const size_t o = (size_t)(tn >> 1) * CO * CI
                           + (size_t)(tn & 1) * 32;
            #pragma unroll
            for (int nt = 0; nt < 4; ++nt)
                bnxt[nt] = *(const short8*)(wt_lane + o + nt * 16 * CI);
        }

        const int pb   = pxo + dw;                       // pixel for mt=0
        const int g0   = (pb + (pb >> 3)) & 7;
        const int kc4q = kc * 4 + quad;
        const char* abase = ldsA + (size_t)((rhalf + dh) * WP + pb) * 128;

        short8 af[4];
        #pragma unroll
        for (int mt = 0; mt < 4; ++mt) {
            const int s = ((g0 + 2 * mt) & 7) ^ kc4q;
            af[mt] = *(const short8*)(abase + mt * 16 * 128 + s * 16);
        }

        #pragma unroll
        for (int mt = 0; mt < 4; ++mt)
            #pragma unroll
            for (int nt = 0; nt < 4; ++nt)
                acc[mt][nt] = __builtin_amdgcn_mfma_f32_16x16x32_bf16(
                    af[mt], bcur[nt], acc[mt][nt], 0, 0, 0);

        #pragma unroll
        for (int nt = 0; nt < 4; ++nt) bcur[nt] = bnxt[nt];
    }

    // ---- epilogue: min over co, *2 ----
    // lane holds D[m = 64wm+16mt+4quad+reg][n = n0+16nt+l15]
    float pm[4][4];
    #pragma unroll
    for (int mt = 0; mt < 4; ++mt)
        #pragma unroll
        for (int reg = 0; reg < 4; ++reg) {
            float t0 = fminf(acc[mt][0][reg], acc[mt][1][reg]);
            float t1 = fminf(acc[mt][2][reg], acc[mt][3][reg]);
            pm[mt][reg] = fminf(t0, t1);
        }
    #pragma unroll
    for (int mask = 1; mask <= 8; mask <<= 1)
        #pragma unroll
        for (int mt = 0; mt < 4; ++mt)
            #pragma unroll
            for (int reg = 0; reg < 4; ++reg)
                pm[mt][reg] = fminf(pm[mt][reg],
                                    __shfl_xor(pm[mt][reg], mask, 64));
    if (l15 == 0) {
        #pragma unroll
        for (int mt = 0; mt < 4; ++mt)
            #pragma unroll
            for (int reg = 0; reg < 4; ++reg)
                scratch[wn][(wm << 6) + (mt << 4) + (quad << 2) + reg]
                    = pm[mt][reg];
    }
    __syncthreads();
    if (tid < 256) {
        float vv = fminf(scratch[0][tid], scratch[1][tid]) * 2.0f;
        out[((size_t)b * HH + 2 * bx + (tid >> 7)) * WW + (tid & 127)] = vv;
    }
}

// ---------------- fallback (round-1 direct conv) ----------------

#define COT 16
__global__ __launch_bounds__(256) void conv_min_fallback(
    const float* __restrict__ x, const float* __restrict__ Wt,
    float* __restrict__ out)
{
    const int b  = blockIdx.y;
    const int h  = blockIdx.x * 2 + (threadIdx.x >> 7);
    const int w  = threadIdx.x & 127;
    const bool r0 = h > 0, r2 = h < HH - 1, c0 = w > 0, c2 = w < WW - 1;
    const float* xb = x + (size_t)b * CI * HH * WW;
    float vmin = 3.4e38f;
    for (int cb = 0; cb < CO; cb += COT) {
        float acc[COT];
        #pragma unroll
        for (int u = 0; u < COT; ++u) acc[u] = 0.0f;
        #pragma unroll 1
        for (int ci = 0; ci < CI; ++ci) {
            const float* xp = xb + ((size_t)ci * HH + h) * WW + w;
            float xv[9];
            xv[0] = (r0 && c0) ? xp[-WW - 1] : 0.0f;
            xv[1] =  r0        ? xp[-WW    ] : 0.0f;
            xv[2] = (r0 && c2) ? xp[-WW + 1] : 0.0f;
            xv[3] =        c0  ? xp[-1     ] : 0.0f;
            xv[4] =              xp[0      ];
            xv[5] =        c2  ? xp[1      ] : 0.0f;
            xv[6] = (r2 && c0) ? xp[ WW - 1] : 0.0f;
            xv[7] =  r2        ? xp[ WW    ] : 0.0f;
            xv[8] = (r2 && c2) ? xp[ WW + 1] : 0.0f;
            #pragma unroll
            for (int u = 0; u < COT; ++u) {
                const float* wp = Wt + ((size_t)(cb + u) * CI + ci) * 9;
                acc[u] += wp[0]*xv[0] + wp[1]*xv[1] + wp[2]*xv[2]
                        + wp[3]*xv[3] + wp[4]*xv[4] + wp[5]*xv[5]
                        + wp[6]*xv[6] + wp[7]*xv[7] + wp[8]*xv[8];
            }
        }
        #pragma unroll
        for (int u = 0; u < COT; ++u) vmin = fminf(vmin, acc[u]);
    }
    out[((size_t)b * HH + h) * WW + w] = vmin * 2.0f;
}

// ---------------- launch ----------------

extern "C" void kernel_launch(void* const* d_in, const int* in_sizes, int n_in,
                              void* d_out, int out_size, void* d_ws, size_t ws_size,
                              hipStream_t stream) {
    const float* x  = (const float*)d_in[0];   // (32,64,128,128)
    const float* Ws = (const float*)d_in[1];   // (128,64,3,3)
    float* out = (float*)d_out;                // (32,1,128,128)

    if (ws_size < WT_BYTES) {
        dim3 grid(HH / 2, 32);
        conv_min_fallback<<<grid, 256, 0, stream>>>(x, Ws, out);
        return;
    }

    unsigned short* wt = (unsigned short*)d_ws;

    prep_w<<<(9 * CO * CI + 255) / 256, 256, 0, stream>>>(Ws, wt);
    conv_fused<<<dim3(HH / 2, 32), 512, 0, stream>>>(x, wt, out);
}